// Round 13
// baseline (269.898 us; speedup 1.0000x reference)
//
#include <hip/hip_runtime.h>
#include <hip/hip_bf16.h>
#include <math.h>

#define FIN 128
#define FH  32
#define FO  64
#define NG  64
#define RW  256      // dsts per range (power of 2)
#define NR_MAX 256

__device__ __forceinline__ float lrelu(float x) { return x >= 0.f ? x : 0.2f * x; }

// ---------------- init scratch ----------------
__global__ void k_init(int* rcnt, float* psum, int* pcnt, int NR) {
  int i = blockIdx.x * blockDim.x + threadIdx.x;
  if (i < NR) rcnt[i] = 0;
  if (i < NG * FO) psum[i] = 0.f;
  if (i < NG) pcnt[i] = 0;
}

// ---------------- edge histogram over dst ranges (LDS-aggregated) ----------------
__global__ void k_hist(const int* __restrict__ ei, int* rcnt, int E, int ET, int NR) {
  __shared__ int sh[NR_MAX];
  for (int i = threadIdx.x; i < NR; i += blockDim.x) sh[i] = 0;
  __syncthreads();
  int stride = gridDim.x * blockDim.x;
  for (int e = blockIdx.x * blockDim.x + threadIdx.x; e < ET; e += stride) {
    int dst = (e < E) ? ei[E + e] : (e - E);
    atomicAdd(&sh[dst >> 8], 1);
  }
  __syncthreads();
  for (int i = threadIdx.x; i < NR; i += blockDim.x)
    if (sh[i]) atomicAdd(&rcnt[i], sh[i]);
}

// ---------------- scan range counts -> segment bases; init reservation ctrs ----------------
__global__ void k_scanr(const int* __restrict__ rcnt, int* rbase, int* rfill,
                        int NR, int ET) {
  __shared__ int sh[NR_MAX];
  int t = threadIdx.x;
  sh[t] = (t < NR) ? rcnt[t] : 0;
  __syncthreads();
  for (int off = 1; off < NR_MAX; off <<= 1) {
    int u = (t >= off) ? sh[t - off] : 0;
    __syncthreads();
    sh[t] += u;
    __syncthreads();
  }
  if (t < NR) {
    int b = (t == 0) ? 0 : sh[t - 1];
    rbase[t] = b;
    rfill[t] = b;
  }
  if (t == 0) rbase[NR] = ET;
}

// ---------------- bucket edges into per-range segments (block reservations) ----------------
__global__ void k_bucket(const int* __restrict__ ei, int* rfill, int2* ebuf,
                         int E, int ET, int NR, int CH) {
  __shared__ int cntS[NR_MAX], baseS[NR_MAX], fillS[NR_MAX];
  int beg = blockIdx.x * CH;
  int end = beg + CH; if (end > ET) end = ET;
  for (int i = threadIdx.x; i < NR; i += blockDim.x) { cntS[i] = 0; fillS[i] = 0; }
  __syncthreads();
  for (int e = beg + threadIdx.x; e < end; e += blockDim.x) {
    int dst = (e < E) ? ei[E + e] : (e - E);
    atomicAdd(&cntS[dst >> 8], 1);
  }
  __syncthreads();
  for (int i = threadIdx.x; i < NR; i += blockDim.x)
    if (cntS[i]) baseS[i] = atomicAdd(&rfill[i], cntS[i]);
  __syncthreads();
  for (int e = beg + threadIdx.x; e < end; e += blockDim.x) {
    int src, dst;
    if (e < E) { dst = ei[E + e]; src = ei[e]; }
    else { src = dst = e - E; }
    int r = dst >> 8;
    int slot = baseS[r] + atomicAdd(&fillS[r], 1);
    ebuf[slot] = make_int2(src, dst);
  }
}

// ---------------- per-range local CSR build (LDS-only atomics) ----------------
__global__ void k_build(const int2* __restrict__ ebuf, const int* __restrict__ rbase,
                        int* ptr, int* esrc, int N, int NR, int ET) {
  __shared__ int cnt[RW], lp[RW], fil[RW];
  int r = blockIdx.x;
  int lo = r << 8;
  int t = threadIdx.x;              // 256 threads
  int sb = rbase[r], se = rbase[r + 1];
  cnt[t] = 0; fil[t] = 0;
  __syncthreads();
  for (int i = sb + t; i < se; i += RW) {
    int d = ebuf[i].y;
    atomicAdd(&cnt[d - lo], 1);
  }
  __syncthreads();
  // exclusive scan of cnt -> lp
  lp[t] = cnt[t];
  __syncthreads();
  for (int off = 1; off < RW; off <<= 1) {
    int u = (t >= off) ? lp[t - off] : 0;
    __syncthreads();
    lp[t] += u;
    __syncthreads();
  }
  int excl = (t == 0) ? 0 : lp[t - 1];
  __syncthreads();
  lp[t] = excl;
  __syncthreads();
  int idx = lo + t;
  if (idx < N) ptr[idx] = sb + excl;
  if (r == NR - 1 && t == 0) ptr[N] = ET;
  for (int i = sb + t; i < se; i += RW) {
    int2 p = ebuf[i];
    int ld = p.y - lo;
    int pos = sb + lp[ld] + atomicAdd(&fil[ld], 1);
    esrc[pos] = p.x;
  }
}

// ---------------- h1 = x @ W1 ; s1 = h1@a_src ; d1 = h1@a_dst ----------------
__global__ void k_mm1(const float* __restrict__ x, const float* __restrict__ W1,
                      const float* __restrict__ a_src, const float* __restrict__ a_dst,
                      float* h1, float* s1, float* d1, int N) {
  __shared__ float Ws[FIN * FH];    // 16 KB
  int t = threadIdx.x;
  for (int i = t; i < FIN * FH; i += 256) Ws[i] = W1[i];
  __syncthreads();
  int node = blockIdx.x * 8 + (t >> 5);
  int f = t & 31;
  if (node >= N) return;
  const float* xr = x + (size_t)node * FIN;
  float acc = 0.f;
#pragma unroll 8
  for (int k = 0; k < FIN; ++k) acc = fmaf(xr[k], Ws[k * FH + f], acc);
  h1[node * FH + f] = acc;
  float sv = acc * a_src[f];
  float dv = acc * a_dst[f];
#pragma unroll
  for (int off = 16; off; off >>= 1) { sv += __shfl_xor(sv, off, 32); dv += __shfl_xor(dv, off, 32); }
  if (f == 0) { s1[node] = sv; d1[node] = dv; }
}

// ---------------- h2 = o1 @ W2 ; s2,d2 ----------------
__global__ void k_mm2(const float* __restrict__ o1, const float* __restrict__ W2,
                      const float* __restrict__ a_src, const float* __restrict__ a_dst,
                      float* h2, float* s2, float* d2, int N) {
  __shared__ float Ws[FH * FO];     // 8 KB
  int t = threadIdx.x;
  for (int i = t; i < FH * FO; i += 256) Ws[i] = W2[i];
  __syncthreads();
  int node = blockIdx.x * 4 + (t >> 6);
  int f = t & 63;
  if (node >= N) return;
  const float* xr = o1 + (size_t)node * FH;
  float acc = 0.f;
#pragma unroll
  for (int k = 0; k < FH; ++k) acc = fmaf(xr[k], Ws[k * FO + f], acc);
  h2[node * FO + f] = acc;
  float sv = acc * a_src[f];
  float dv = acc * a_dst[f];
#pragma unroll
  for (int off = 32; off; off >>= 1) { sv += __shfl_xor(sv, off); dv += __shfl_xor(dv, off); }
  if (f == 0) { s2[node] = sv; d2[node] = dv; }
}

// ---------------- layer-1 gather: EXACT baseline source (FP math frozen) ----------------
__global__ void k_gat1(const int* __restrict__ ptr, const int* __restrict__ esrc,
                       const float* __restrict__ s1, const float* __restrict__ d1,
                       const float* __restrict__ h1, const float* __restrict__ b1,
                       float* o1, int N) {
  int wid = (blockIdx.x * blockDim.x + threadIdx.x) >> 6;
  int lane = threadIdx.x & 63;
  if (wid >= N) return;
  int beg = ptr[wid], end = ptr[wid + 1];
  float dn = d1[wid];
  float mx = -INFINITY;
  for (int i = beg + lane; i < end; i += 64)
    mx = fmaxf(mx, lrelu(s1[esrc[i]] + dn));
#pragma unroll
  for (int off = 32; off; off >>= 1) mx = fmaxf(mx, __shfl_xor(mx, off));
  int half = lane >> 5;
  int f = lane & 31;
  float acc = 0.f, zl = 0.f;
  for (int cbeg = beg; cbeg < end; cbeg += 64) {
    int i = cbeg + lane;
    float w = 0.f; int s = 0;
    if (i < end) {
      s = esrc[i];
      w = __expf(lrelu(s1[s] + dn) - mx);
    }
    zl += w;
    int cnt = end - cbeg; if (cnt > 64) cnt = 64;
    for (int j = half; j < cnt; j += 2) {
      float wj = __shfl(w, j);
      int sj = __shfl(s, j);
      acc = fmaf(wj, h1[sj * FH + f], acc);
    }
  }
  acc += __shfl_xor(acc, 32);
#pragma unroll
  for (int off = 32; off; off >>= 1) zl += __shfl_xor(zl, off);
  if (lane < 32) {
    float v = acc / zl + b1[f];
    v = v > 0.f ? v : __expf(v) - 1.f;   // ELU
    o1[wid * FH + f] = v;
  }
}

// ---------------- layer-2 gather: pinned-fmac x8/4/2/1 unroll + first-chunk ev cache ----------------
// ev cache: the max pass already computes lrelu(s2[esrc[i]]+dn) for the first
// chunk; keep (s, ev) in registers and reuse in the w pass (value-identical,
// no FP op added/removed/reordered). Acc chain pinned in asm, strictly
// j-ascending across all tiers => bit-identical to the sequential chain.
__global__ void k_gat2(const int* __restrict__ ptr, const int* __restrict__ esrc,
                       const float* __restrict__ s2, const float* __restrict__ d2,
                       const float* __restrict__ h2, const float* __restrict__ b2,
                       float* h2o, int N) {
  int wid = (blockIdx.x * blockDim.x + threadIdx.x) >> 6;
  int lane = threadIdx.x & 63;
  if (wid >= N) return;
  int beg = ptr[wid], end = ptr[wid + 1];
  float dn = d2[wid];
  float mx = -INFINITY;
  int   sF = 0;       // first-chunk cached src
  float evF = 0.f;    // first-chunk cached e-value
  {
    int i = beg + lane;
    if (i < end) {
      sF = esrc[i];
      evF = lrelu(s2[sF] + dn);
      mx = evF;                      // fmaxf(-INF, ev) == ev
    }
    for (i += 64; i < end; i += 64)
      mx = fmaxf(mx, lrelu(s2[esrc[i]] + dn));
  }
#pragma unroll
  for (int off = 32; off; off >>= 1) mx = fmaxf(mx, __shfl_xor(mx, off));
  float acc = 0.f, zl = 0.f;
  for (int cbeg = beg; cbeg < end; cbeg += 64) {
    int i = cbeg + lane;
    float w = 0.f; int s = 0;
    if (i < end) {
      if (cbeg == beg) { s = sF; w = __expf(evF - mx); }
      else { s = esrc[i]; w = __expf(lrelu(s2[s] + dn) - mx); }
    }
    zl += w;
    int cnt = end - cbeg; if (cnt > 64) cnt = 64;
    int j = 0;
    for (; j + 7 < cnt; j += 8) {
      float w0 = __shfl(w, j);     int p0 = __shfl(s, j);
      float w1 = __shfl(w, j + 1); int p1 = __shfl(s, j + 1);
      float w2 = __shfl(w, j + 2); int p2 = __shfl(s, j + 2);
      float w3 = __shfl(w, j + 3); int p3 = __shfl(s, j + 3);
      float w4 = __shfl(w, j + 4); int p4 = __shfl(s, j + 4);
      float w5 = __shfl(w, j + 5); int p5 = __shfl(s, j + 5);
      float w6 = __shfl(w, j + 6); int p6 = __shfl(s, j + 6);
      float w7 = __shfl(w, j + 7); int p7 = __shfl(s, j + 7);
      float a0 = h2[p0 * FO + lane];
      float a1 = h2[p1 * FO + lane];
      float a2 = h2[p2 * FO + lane];
      float a3 = h2[p3 * FO + lane];
      float a4 = h2[p4 * FO + lane];
      float a5 = h2[p5 * FO + lane];
      float a6 = h2[p6 * FO + lane];
      float a7 = h2[p7 * FO + lane];
      asm volatile("v_fmac_f32 %0, %1, %2" : "+v"(acc) : "v"(w0), "v"(a0));
      asm volatile("v_fmac_f32 %0, %1, %2" : "+v"(acc) : "v"(w1), "v"(a1));
      asm volatile("v_fmac_f32 %0, %1, %2" : "+v"(acc) : "v"(w2), "v"(a2));
      asm volatile("v_fmac_f32 %0, %1, %2" : "+v"(acc) : "v"(w3), "v"(a3));
      asm volatile("v_fmac_f32 %0, %1, %2" : "+v"(acc) : "v"(w4), "v"(a4));
      asm volatile("v_fmac_f32 %0, %1, %2" : "+v"(acc) : "v"(w5), "v"(a5));
      asm volatile("v_fmac_f32 %0, %1, %2" : "+v"(acc) : "v"(w6), "v"(a6));
      asm volatile("v_fmac_f32 %0, %1, %2" : "+v"(acc) : "v"(w7), "v"(a7));
    }
    if (j + 3 < cnt) {
      float w0 = __shfl(w, j);     int p0 = __shfl(s, j);
      float w1 = __shfl(w, j + 1); int p1 = __shfl(s, j + 1);
      float w2 = __shfl(w, j + 2); int p2 = __shfl(s, j + 2);
      float w3 = __shfl(w, j + 3); int p3 = __shfl(s, j + 3);
      float a0 = h2[p0 * FO + lane];
      float a1 = h2[p1 * FO + lane];
      float a2 = h2[p2 * FO + lane];
      float a3 = h2[p3 * FO + lane];
      asm volatile("v_fmac_f32 %0, %1, %2" : "+v"(acc) : "v"(w0), "v"(a0));
      asm volatile("v_fmac_f32 %0, %1, %2" : "+v"(acc) : "v"(w1), "v"(a1));
      asm volatile("v_fmac_f32 %0, %1, %2" : "+v"(acc) : "v"(w2), "v"(a2));
      asm volatile("v_fmac_f32 %0, %1, %2" : "+v"(acc) : "v"(w3), "v"(a3));
      j += 4;
    }
    if (j + 1 < cnt) {
      float w0 = __shfl(w, j);     int p0 = __shfl(s, j);
      float w1 = __shfl(w, j + 1); int p1 = __shfl(s, j + 1);
      float a0 = h2[p0 * FO + lane];
      float a1 = h2[p1 * FO + lane];
      asm volatile("v_fmac_f32 %0, %1, %2" : "+v"(acc) : "v"(w0), "v"(a0));
      asm volatile("v_fmac_f32 %0, %1, %2" : "+v"(acc) : "v"(w1), "v"(a1));
      j += 2;
    }
    if (j < cnt) {
      float wj = __shfl(w, j);
      int sj = __shfl(s, j);
      float aj = h2[sj * FO + lane];
      asm volatile("v_fmac_f32 %0, %1, %2" : "+v"(acc) : "v"(wj), "v"(aj));
    }
  }
#pragma unroll
  for (int off = 32; off; off >>= 1) zl += __shfl_xor(zl, off);
  h2o[wid * FO + lane] = acc / zl + b2[lane];
}

// ---------------- mean-pool over sorted batch ----------------
__global__ void k_pool(const float* __restrict__ h2o, const int* __restrict__ batch,
                       float* psum, int* pcnt, int N) {
  const int NPW = 32;  // nodes per wave
  int wib = threadIdx.x >> 6;
  int lane = threadIdx.x & 63;
  int nbeg = (blockIdx.x * 4 + wib) * NPW;
  if (nbeg >= N) return;
  int nend = nbeg + NPW; if (nend > N) nend = N;
  int cur = batch[nbeg];
  float acc = 0.f; int c = 0;
  for (int n = nbeg; n < nend; ++n) {
    int g = batch[n];
    if (g != cur) {
      atomicAdd(&psum[cur * FO + lane], acc);
      if (lane == 0) atomicAdd(&pcnt[cur], c);
      acc = 0.f; c = 0; cur = g;
    }
    acc += h2o[(size_t)n * FO + lane];
    c++;
  }
  atomicAdd(&psum[cur * FO + lane], acc);
  if (lane == 0) atomicAdd(&pcnt[cur], c);
}

__global__ void k_fin(const float* psum, const int* pcnt, float* out) {
  int i = blockIdx.x * blockDim.x + threadIdx.x;
  if (i < NG * FO) {
    int g = i >> 6;   // FO == 64
    out[i] = psum[i] / fmaxf((float)pcnt[g], 1.f);
  }
}

extern "C" void kernel_launch(void* const* d_in, const int* in_sizes, int n_in,
                              void* d_out, int out_size, void* d_ws, size_t ws_size,
                              hipStream_t stream) {
  const float* x    = (const float*)d_in[0];
  const int*   ei   = (const int*)d_in[1];
  const int*   bat  = (const int*)d_in[2];
  const float* W1   = (const float*)d_in[3];
  const float* as1  = (const float*)d_in[4];
  const float* ad1  = (const float*)d_in[5];
  const float* b1   = (const float*)d_in[6];
  const float* W2   = (const float*)d_in[7];
  const float* as2  = (const float*)d_in[8];
  const float* ad2  = (const float*)d_in[9];
  const float* b2   = (const float*)d_in[10];
  float* out = (float*)d_out;

  int N  = in_sizes[0] / FIN;
  int E  = in_sizes[1] / 2;
  int ET = E + N;
  int NR = (N + RW - 1) / RW;            // dst ranges (<= 256)

  char* p = (char*)d_ws;
  auto carve = [&](size_t bytes) -> void* {
    void* r = (void*)p; p += (bytes + 255) & ~(size_t)255; return r;
  };
  float* h1   = (float*)carve((size_t)N * FH * 4);
  float* s1   = (float*)carve((size_t)N * 4);
  float* d1   = (float*)carve((size_t)N * 4);
  float* o1   = (float*)carve((size_t)N * FH * 4);
  float* h2   = (float*)carve((size_t)N * FO * 4);
  float* s2   = (float*)carve((size_t)N * 4);
  float* d2   = (float*)carve((size_t)N * 4);
  float* h2o  = (float*)carve((size_t)N * FO * 4);
  int*   ptr  = (int*)carve((size_t)(N + 1) * 4);
  int*   esrc = (int*)carve((size_t)ET * 4);
  float* psum = (float*)carve((size_t)NG * FO * 4);
  int*   pcnt = (int*)carve((size_t)NG * 4);
  int*   rcnt = (int*)carve((size_t)(NR + 1) * 4);
  int*   rbase= (int*)carve((size_t)(NR + 1) * 4);
  int*   rfil = (int*)carve((size_t)(NR + 1) * 4);
  int2*  ebuf = (int2*)carve((size_t)ET * 8);

  int BA = 1024;                         // bucket blocks
  int CH = (ET + BA - 1) / BA;           // bucket chunk

  k_init   <<<(NG * FO + 255) / 256, 256, 0, stream>>>(rcnt, psum, pcnt, NR);
  k_mm1    <<<(N + 7) / 8,     256, 0, stream>>>(x, W1, as1, ad1, h1, s1, d1, N);
  k_hist   <<<512,             256, 0, stream>>>(ei, rcnt, E, ET, NR);
  k_scanr  <<<1,               256, 0, stream>>>(rcnt, rbase, rfil, NR, ET);
  k_bucket <<<BA,              256, 0, stream>>>(ei, rfil, ebuf, E, ET, NR, CH);
  k_build  <<<NR,              256, 0, stream>>>(ebuf, rbase, ptr, esrc, N, NR, ET);
  k_gat1   <<<(N + 3) / 4,     256, 0, stream>>>(ptr, esrc, s1, d1, h1, b1, o1, N);
  k_mm2    <<<(N + 3) / 4,     256, 0, stream>>>(o1, W2, as2, ad2, h2, s2, d2, N);
  k_gat2   <<<(N + 3) / 4,     256, 0, stream>>>(ptr, esrc, s2, d2, h2, b2, h2o, N);
  k_pool   <<<(N + 127) / 128, 256, 0, stream>>>(h2o, bat, psum, pcnt, N);
  k_fin    <<<(NG * FO + 255) / 256, 256, 0, stream>>>(psum, pcnt, out);
}

// Round 14
// 265.874 us; speedup vs baseline: 1.0151x; 1.0151x over previous
//
#include <hip/hip_runtime.h>
#include <hip/hip_bf16.h>
#include <math.h>

#define FIN 128
#define FH  32
#define FO  64
#define NG  64
#define RW  256      // dsts per range (power of 2)
#define NR_MAX 256

__device__ __forceinline__ float lrelu(float x) { return x >= 0.f ? x : 0.2f * x; }

// ---------------- edge histogram over dst ranges (LDS-aggregated) ----------------
__global__ void k_hist(const int* __restrict__ ei, int* rcnt, int E, int ET, int NR) {
  __shared__ int sh[NR_MAX];
  for (int i = threadIdx.x; i < NR; i += blockDim.x) sh[i] = 0;
  __syncthreads();
  int stride = gridDim.x * blockDim.x;
  for (int e = blockIdx.x * blockDim.x + threadIdx.x; e < ET; e += stride) {
    int dst = (e < E) ? ei[E + e] : (e - E);
    atomicAdd(&sh[dst >> 8], 1);
  }
  __syncthreads();
  for (int i = threadIdx.x; i < NR; i += blockDim.x)
    if (sh[i]) atomicAdd(&rcnt[i], sh[i]);
}

// ---------------- scan range counts -> segment bases; init reservation ctrs ----------------
__global__ void k_scanr(const int* __restrict__ rcnt, int* rbase, int* rfill,
                        int NR, int ET) {
  __shared__ int sh[NR_MAX];
  int t = threadIdx.x;
  sh[t] = (t < NR) ? rcnt[t] : 0;
  __syncthreads();
  for (int off = 1; off < NR_MAX; off <<= 1) {
    int u = (t >= off) ? sh[t - off] : 0;
    __syncthreads();
    sh[t] += u;
    __syncthreads();
  }
  if (t < NR) {
    int b = (t == 0) ? 0 : sh[t - 1];
    rbase[t] = b;
    rfill[t] = b;
  }
  if (t == 0) rbase[NR] = ET;
}

// ---------------- bucket edges into per-range segments (packed 4B records) ----------------
__global__ void k_bucket(const int* __restrict__ ei, int* rfill, unsigned* ebuf,
                         int E, int ET, int NR, int CH) {
  __shared__ int cntS[NR_MAX], baseS[NR_MAX], fillS[NR_MAX];
  int beg = blockIdx.x * CH;
  int end = beg + CH; if (end > ET) end = ET;
  for (int i = threadIdx.x; i < NR; i += blockDim.x) { cntS[i] = 0; fillS[i] = 0; }
  __syncthreads();
  for (int e = beg + threadIdx.x; e < end; e += blockDim.x) {
    int dst = (e < E) ? ei[E + e] : (e - E);
    atomicAdd(&cntS[dst >> 8], 1);
  }
  __syncthreads();
  for (int i = threadIdx.x; i < NR; i += blockDim.x)
    if (cntS[i]) baseS[i] = atomicAdd(&rfill[i], cntS[i]);
  __syncthreads();
  for (int e = beg + threadIdx.x; e < end; e += blockDim.x) {
    int src, dst;
    if (e < E) { dst = ei[E + e]; src = ei[e]; }
    else { src = dst = e - E; }
    int r = dst >> 8;
    int slot = baseS[r] + atomicAdd(&fillS[r], 1);
    ebuf[slot] = ((unsigned)(dst & 255) << 24) | (unsigned)src;
  }
}

// ---------------- per-range local CSR build (LDS-only atomics, packed reads) ----------------
__global__ void k_build(const unsigned* __restrict__ ebuf, const int* __restrict__ rbase,
                        int* ptr, int* esrc, int N, int NR, int ET) {
  __shared__ int cnt[RW], lp[RW], fil[RW];
  int r = blockIdx.x;
  int lo = r << 8;
  int t = threadIdx.x;              // 256 threads
  int sb = rbase[r], se = rbase[r + 1];
  cnt[t] = 0; fil[t] = 0;
  __syncthreads();
  for (int i = sb + t; i < se; i += RW) {
    int ld = (int)(ebuf[i] >> 24);
    atomicAdd(&cnt[ld], 1);
  }
  __syncthreads();
  // exclusive scan of cnt -> lp
  lp[t] = cnt[t];
  __syncthreads();
  for (int off = 1; off < RW; off <<= 1) {
    int u = (t >= off) ? lp[t - off] : 0;
    __syncthreads();
    lp[t] += u;
    __syncthreads();
  }
  int excl = (t == 0) ? 0 : lp[t - 1];
  __syncthreads();
  lp[t] = excl;
  __syncthreads();
  int idx = lo + t;
  if (idx < N) ptr[idx] = sb + excl;
  if (r == NR - 1 && t == 0) ptr[N] = ET;
  for (int i = sb + t; i < se; i += RW) {
    unsigned pv = ebuf[i];
    int ld = (int)(pv >> 24);
    int src = (int)(pv & 0x00FFFFFFu);
    int pos = sb + lp[ld] + atomicAdd(&fil[ld], 1);
    esrc[pos] = src;
  }
}

// ---------------- h1 = x @ W1 ; s1 = h1@a_src ; d1 = h1@a_dst ----------------
__global__ void k_mm1(const float* __restrict__ x, const float* __restrict__ W1,
                      const float* __restrict__ a_src, const float* __restrict__ a_dst,
                      float* h1, float* s1, float* d1, int N) {
  __shared__ float Ws[FIN * FH];    // 16 KB
  int t = threadIdx.x;
  for (int i = t; i < FIN * FH; i += 256) Ws[i] = W1[i];
  __syncthreads();
  int node = blockIdx.x * 8 + (t >> 5);
  int f = t & 31;
  if (node >= N) return;
  const float* xr = x + (size_t)node * FIN;
  float acc = 0.f;
#pragma unroll 8
  for (int k = 0; k < FIN; ++k) acc = fmaf(xr[k], Ws[k * FH + f], acc);
  h1[node * FH + f] = acc;
  float sv = acc * a_src[f];
  float dv = acc * a_dst[f];
#pragma unroll
  for (int off = 16; off; off >>= 1) { sv += __shfl_xor(sv, off, 32); dv += __shfl_xor(dv, off, 32); }
  if (f == 0) { s1[node] = sv; d1[node] = dv; }
}

// ---------------- h2 = o1 @ W2 ; s2,d2 ----------------
__global__ void k_mm2(const float* __restrict__ o1, const float* __restrict__ W2,
                      const float* __restrict__ a_src, const float* __restrict__ a_dst,
                      float* h2, float* s2, float* d2, int N) {
  __shared__ float Ws[FH * FO];     // 8 KB
  int t = threadIdx.x;
  for (int i = t; i < FH * FO; i += 256) Ws[i] = W2[i];
  __syncthreads();
  int node = blockIdx.x * 4 + (t >> 6);
  int f = t & 63;
  if (node >= N) return;
  const float* xr = o1 + (size_t)node * FH;
  float acc = 0.f;
#pragma unroll
  for (int k = 0; k < FH; ++k) acc = fmaf(xr[k], Ws[k * FO + f], acc);
  h2[node * FO + f] = acc;
  float sv = acc * a_src[f];
  float dv = acc * a_dst[f];
#pragma unroll
  for (int off = 32; off; off >>= 1) { sv += __shfl_xor(sv, off); dv += __shfl_xor(dv, off); }
  if (f == 0) { s2[node] = sv; d2[node] = dv; }
}

// ---------------- layer-1 gather: EXACT baseline source (FP math frozen) ----------------
__global__ void k_gat1(const int* __restrict__ ptr, const int* __restrict__ esrc,
                       const float* __restrict__ s1, const float* __restrict__ d1,
                       const float* __restrict__ h1, const float* __restrict__ b1,
                       float* o1, int N) {
  int wid = (blockIdx.x * blockDim.x + threadIdx.x) >> 6;
  int lane = threadIdx.x & 63;
  if (wid >= N) return;
  int beg = ptr[wid], end = ptr[wid + 1];
  float dn = d1[wid];
  float mx = -INFINITY;
  for (int i = beg + lane; i < end; i += 64)
    mx = fmaxf(mx, lrelu(s1[esrc[i]] + dn));
#pragma unroll
  for (int off = 32; off; off >>= 1) mx = fmaxf(mx, __shfl_xor(mx, off));
  int half = lane >> 5;
  int f = lane & 31;
  float acc = 0.f, zl = 0.f;
  for (int cbeg = beg; cbeg < end; cbeg += 64) {
    int i = cbeg + lane;
    float w = 0.f; int s = 0;
    if (i < end) {
      s = esrc[i];
      w = __expf(lrelu(s1[s] + dn) - mx);
    }
    zl += w;
    int cnt = end - cbeg; if (cnt > 64) cnt = 64;
    for (int j = half; j < cnt; j += 2) {
      float wj = __shfl(w, j);
      int sj = __shfl(s, j);
      acc = fmaf(wj, h1[sj * FH + f], acc);
    }
  }
  acc += __shfl_xor(acc, 32);
#pragma unroll
  for (int off = 32; off; off >>= 1) zl += __shfl_xor(zl, off);
  if (lane < 32) {
    float v = acc / zl + b1[f];
    v = v > 0.f ? v : __expf(v) - 1.f;   // ELU
    o1[wid * FH + f] = v;
  }
}

// ---------------- layer-2 gather: pinned-fmac x8 unroll (R12-exact source) ----------------
__global__ void k_gat2(const int* __restrict__ ptr, const int* __restrict__ esrc,
                       const float* __restrict__ s2, const float* __restrict__ d2,
                       const float* __restrict__ h2, const float* __restrict__ b2,
                       float* h2o, int N) {
  int wid = (blockIdx.x * blockDim.x + threadIdx.x) >> 6;
  int lane = threadIdx.x & 63;
  if (wid >= N) return;
  int beg = ptr[wid], end = ptr[wid + 1];
  float dn = d2[wid];
  float mx = -INFINITY;
  for (int i = beg + lane; i < end; i += 64)
    mx = fmaxf(mx, lrelu(s2[esrc[i]] + dn));
#pragma unroll
  for (int off = 32; off; off >>= 1) mx = fmaxf(mx, __shfl_xor(mx, off));
  float acc = 0.f, zl = 0.f;
  for (int cbeg = beg; cbeg < end; cbeg += 64) {
    int i = cbeg + lane;
    float w = 0.f; int s = 0;
    if (i < end) {
      s = esrc[i];
      w = __expf(lrelu(s2[s] + dn) - mx);
    }
    zl += w;
    int cnt = end - cbeg; if (cnt > 64) cnt = 64;
    int j = 0;
    for (; j + 7 < cnt; j += 8) {
      float w0 = __shfl(w, j);     int p0 = __shfl(s, j);
      float w1 = __shfl(w, j + 1); int p1 = __shfl(s, j + 1);
      float w2 = __shfl(w, j + 2); int p2 = __shfl(s, j + 2);
      float w3 = __shfl(w, j + 3); int p3 = __shfl(s, j + 3);
      float w4 = __shfl(w, j + 4); int p4 = __shfl(s, j + 4);
      float w5 = __shfl(w, j + 5); int p5 = __shfl(s, j + 5);
      float w6 = __shfl(w, j + 6); int p6 = __shfl(s, j + 6);
      float w7 = __shfl(w, j + 7); int p7 = __shfl(s, j + 7);
      float a0 = h2[p0 * FO + lane];
      float a1 = h2[p1 * FO + lane];
      float a2 = h2[p2 * FO + lane];
      float a3 = h2[p3 * FO + lane];
      float a4 = h2[p4 * FO + lane];
      float a5 = h2[p5 * FO + lane];
      float a6 = h2[p6 * FO + lane];
      float a7 = h2[p7 * FO + lane];
      asm volatile("v_fmac_f32 %0, %1, %2" : "+v"(acc) : "v"(w0), "v"(a0));
      asm volatile("v_fmac_f32 %0, %1, %2" : "+v"(acc) : "v"(w1), "v"(a1));
      asm volatile("v_fmac_f32 %0, %1, %2" : "+v"(acc) : "v"(w2), "v"(a2));
      asm volatile("v_fmac_f32 %0, %1, %2" : "+v"(acc) : "v"(w3), "v"(a3));
      asm volatile("v_fmac_f32 %0, %1, %2" : "+v"(acc) : "v"(w4), "v"(a4));
      asm volatile("v_fmac_f32 %0, %1, %2" : "+v"(acc) : "v"(w5), "v"(a5));
      asm volatile("v_fmac_f32 %0, %1, %2" : "+v"(acc) : "v"(w6), "v"(a6));
      asm volatile("v_fmac_f32 %0, %1, %2" : "+v"(acc) : "v"(w7), "v"(a7));
    }
    for (; j < cnt; ++j) {
      float wj = __shfl(w, j);
      int sj = __shfl(s, j);
      float aj = h2[sj * FO + lane];
      asm volatile("v_fmac_f32 %0, %1, %2" : "+v"(acc) : "v"(wj), "v"(aj));
    }
  }
#pragma unroll
  for (int off = 32; off; off >>= 1) zl += __shfl_xor(zl, off);
  h2o[wid * FO + lane] = acc / zl + b2[lane];
}

// ---------------- mean-pool over sorted batch ----------------
__global__ void k_pool(const float* __restrict__ h2o, const int* __restrict__ batch,
                       float* psum, int* pcnt, int N) {
  const int NPW = 32;  // nodes per wave
  int wib = threadIdx.x >> 6;
  int lane = threadIdx.x & 63;
  int nbeg = (blockIdx.x * 4 + wib) * NPW;
  if (nbeg >= N) return;
  int nend = nbeg + NPW; if (nend > N) nend = N;
  int cur = batch[nbeg];
  float acc = 0.f; int c = 0;
  for (int n = nbeg; n < nend; ++n) {
    int g = batch[n];
    if (g != cur) {
      atomicAdd(&psum[cur * FO + lane], acc);
      if (lane == 0) atomicAdd(&pcnt[cur], c);
      acc = 0.f; c = 0; cur = g;
    }
    acc += h2o[(size_t)n * FO + lane];
    c++;
  }
  atomicAdd(&psum[cur * FO + lane], acc);
  if (lane == 0) atomicAdd(&pcnt[cur], c);
}

__global__ void k_fin(const float* psum, const int* pcnt, float* out) {
  int i = blockIdx.x * blockDim.x + threadIdx.x;
  if (i < NG * FO) {
    int g = i >> 6;   // FO == 64
    out[i] = psum[i] / fmaxf((float)pcnt[g], 1.f);
  }
}

extern "C" void kernel_launch(void* const* d_in, const int* in_sizes, int n_in,
                              void* d_out, int out_size, void* d_ws, size_t ws_size,
                              hipStream_t stream) {
  const float* x    = (const float*)d_in[0];
  const int*   ei   = (const int*)d_in[1];
  const int*   bat  = (const int*)d_in[2];
  const float* W1   = (const float*)d_in[3];
  const float* as1  = (const float*)d_in[4];
  const float* ad1  = (const float*)d_in[5];
  const float* b1   = (const float*)d_in[6];
  const float* W2   = (const float*)d_in[7];
  const float* as2  = (const float*)d_in[8];
  const float* ad2  = (const float*)d_in[9];
  const float* b2   = (const float*)d_in[10];
  float* out = (float*)d_out;

  int N  = in_sizes[0] / FIN;
  int E  = in_sizes[1] / 2;
  int ET = E + N;
  int NR = (N + RW - 1) / RW;            // dst ranges (<= 256)

  char* p = (char*)d_ws;
  auto carve = [&](size_t bytes) -> void* {
    void* r = (void*)p; p += (bytes + 255) & ~(size_t)255; return r;
  };
  float* h1   = (float*)carve((size_t)N * FH * 4);
  float* s1   = (float*)carve((size_t)N * 4);
  float* d1   = (float*)carve((size_t)N * 4);
  float* o1   = (float*)carve((size_t)N * FH * 4);
  float* h2   = (float*)carve((size_t)N * FO * 4);
  float* s2   = (float*)carve((size_t)N * 4);
  float* d2   = (float*)carve((size_t)N * 4);
  float* h2o  = (float*)carve((size_t)N * FO * 4);
  int*   ptr  = (int*)carve((size_t)(N + 1) * 4);
  int*   esrc = (int*)carve((size_t)ET * 4);
  // psum/pcnt/rcnt adjacent: single memset covers them (padding is harmless)
  float* psum = (float*)carve((size_t)NG * FO * 4);
  int*   pcnt = (int*)carve((size_t)NG * 4);
  int*   rcnt = (int*)carve((size_t)(NR + 1) * 4);
  char*  zend = p;
  int*   rbase= (int*)carve((size_t)(NR + 1) * 4);
  int*   rfil = (int*)carve((size_t)(NR + 1) * 4);
  unsigned* ebuf = (unsigned*)carve((size_t)ET * 4);

  int BA = 512;                          // bucket blocks
  int CH = (ET + BA - 1) / BA;           // bucket chunk

  hipMemsetAsync(psum, 0, (size_t)(zend - (char*)psum), stream);
  k_mm1    <<<(N + 7) / 8,     256, 0, stream>>>(x, W1, as1, ad1, h1, s1, d1, N);
  k_hist   <<<512,             256, 0, stream>>>(ei, rcnt, E, ET, NR);
  k_scanr  <<<1,               256, 0, stream>>>(rcnt, rbase, rfil, NR, ET);
  k_bucket <<<BA,              256, 0, stream>>>(ei, rfil, ebuf, E, ET, NR, CH);
  k_build  <<<NR,              256, 0, stream>>>(ebuf, rbase, ptr, esrc, N, NR, ET);
  k_gat1   <<<(N + 3) / 4,     256, 0, stream>>>(ptr, esrc, s1, d1, h1, b1, o1, N);
  k_mm2    <<<(N + 3) / 4,     256, 0, stream>>>(o1, W2, as2, ad2, h2, s2, d2, N);
  k_gat2   <<<(N + 3) / 4,     256, 0, stream>>>(ptr, esrc, s2, d2, h2, b2, h2o, N);
  k_pool   <<<(N + 127) / 128, 256, 0, stream>>>(h2o, bat, psum, pcnt, N);
  k_fin    <<<(NG * FO + 255) / 256, 256, 0, stream>>>(psum, pcnt, out);
}